// Round 9
// baseline (117.438 us; speedup 1.0000x reference)
//
#include <hip/hip_runtime.h>
#include <hip/hip_bf16.h>

// HeteroLinear fused forward on gfx950: out[i] = x[i] @ W[tv[i]] + b[tv[i]]
// N=131072, IN=OUT=256, T=8, tv sorted. HBM floor ~256 MB -> ~41 us.
// R9: R8 + two changes aimed at measured residuals:
//  (1) LDS 128->64 KB: W[t] staged in two col-halves => 2 blocks/CU
//      co-resident (R8 occupancy was 18%, 2 waves/EU -> x-load latency
//      exposed). Cross-block overlap hides DMA-drain barriers.
//  (2) plain stores instead of nontemporal (NT rounds show +20-40 MB WRITE
//      amplification; R1 plain stores hit 131.07 MB exact).
// __launch_bounds__(512,4): 4 waves/EU -> cap 128 VGPR; R8 measured 104.

#define NROWS 131072
#define KD 256
#define ND 256
#define BM 256                      // rows per block
#define NBLK (NROWS / BM)           // 512
#define HC 128                      // cols per staged half

typedef __attribute__((ext_vector_type(8))) short short8;
typedef __attribute__((ext_vector_type(4))) float f32x4;
typedef __attribute__((ext_vector_type(4))) float flt4;

typedef __attribute__((address_space(3))) unsigned int lds_u32_t;
typedef __attribute__((address_space(1))) unsigned int glb_u32_t;

__device__ inline unsigned short f2bf(float f) {
    unsigned int u = __float_as_uint(f);
    u += 0x7FFFu + ((u >> 16) & 1u);   // RNE
    return (unsigned short)(u >> 16);
}

// ---- weight prep: wT[t][n][k] = bf16(w[t][k][n]) ----
__global__ __launch_bounds__(256) void prep_weights(const float* __restrict__ w,
                                                    unsigned short* __restrict__ wT) {
    __shared__ unsigned short L[8][264];
    const int t  = blockIdx.x >> 5;
    const int k0 = (blockIdx.x & 31) * 8;
    const int tid = threadIdx.x;

    #pragma unroll
    for (int i = 0; i < 2; ++i) {
        int idx = i * 256 + tid;
        int kr  = idx >> 6;
        int nq  = idx & 63;
        const flt4* src = (const flt4*)(w + ((size_t)t * 256 + k0 + kr) * 256);
        flt4 v = src[nq];
        #pragma unroll
        for (int j = 0; j < 4; ++j) L[kr][nq * 4 + j] = f2bf(v[j]);
    }
    __syncthreads();

    int n = tid;
    short8 v;
    #pragma unroll
    for (int j = 0; j < 8; ++j) v[j] = (short)L[j][n];
    *(short8*)(wT + ((size_t)t * 256 + n) * 256 + k0) = v;
}

// ---- main GEMM ----
__global__ __launch_bounds__(512, 4) void hetero_gemm(
        const float* __restrict__ x, const int* __restrict__ tv,
        const unsigned short* __restrict__ wT, const float* __restrict__ bias,
        float* __restrict__ out) {
    // Half of W[t]: 128 cols x 256 k, bf16, [local col][k], 512 B per col,
    // XOR-swizzled 16B chunks: LDS chunk c of col holds global chunk c^(col&7).
    __shared__ short Bs[HC * KD];            // 64 KiB -> 2 blocks/CU

    const int tid  = threadIdx.x;
    const int lane = tid & 63;
    const int wv   = tid >> 6;               // 8 waves
    const int cl   = lane & 15;
    const int kg   = lane >> 4;
    const int r0   = blockIdx.x * BM;
    const int rw   = r0 + wv * 32;           // wave's 32-row strip

    const int tmin = tv[r0];
    const int tmax = tv[r0 + BM - 1];
    const int ty0  = tv[rw + cl];            // type of row (m=0)
    const int ty1  = tv[rw + 16 + cl];       // type of row (m=1)
    const int s    = cl & 7;                 // swizzle key (col&7 == cl&7)

    for (int t = tmin; t <= tmax; ++t) {
        #pragma unroll
        for (int half = 0; half < 2; ++half) {
            const int c0 = half * HC;

            if (t > tmin || half > 0)
                __syncthreads();             // all reads of prev half done

            // ---- stage W[t][c0..c0+127][*] -> LDS: 4096 chunks, 8 rounds ----
            {
                const unsigned short* Wt = wT + (size_t)t * (KD * ND);
                #pragma unroll
                for (int rnd = 0; rnd < 8; ++rnd) {
                    int i   = rnd * 512 + tid;   // chunk 0..4095
                    int lc  = i >> 5;            // local col 0..127
                    int c   = i & 31;
                    int sc  = c ^ (lc & 7);      // source-side swizzle
                    const unsigned short* gp = Wt + (size_t)(c0 + lc) * KD + sc * 8;
                    __builtin_amdgcn_global_load_lds(
                        (const glb_u32_t*)gp,
                        (lds_u32_t*)((char*)Bs + (size_t)(rnd * 512 + wv * 64) * 16),
                        16, 0, 0);
                }
            }
            __syncthreads();                 // drain DMA; half ready

            // ---- compute 32 rows x this col-half ----
            f32x4 zero = {0.f, 0.f, 0.f, 0.f};
            f32x4 acc[2][8];
            #pragma unroll
            for (int m = 0; m < 2; ++m)
                #pragma unroll
                for (int n = 0; n < 8; ++n) acc[m][n] = zero;

            short8 a_cur[2], a_nxt[2];
            #pragma unroll
            for (int m = 0; m < 2; ++m) {    // preload ks=0
                const float* ap = x + (size_t)(rw + m * 16 + cl) * KD + kg * 8;
                f32x4 v0 = *(const f32x4*)ap;
                f32x4 v1 = *(const f32x4*)(ap + 4);
                #pragma unroll
                for (int j = 0; j < 4; ++j) {
                    a_cur[m][j]     = (short)f2bf(v0[j]);
                    a_cur[m][4 + j] = (short)f2bf(v1[j]);
                }
            }

            #pragma unroll
            for (int ks = 0; ks < 8; ++ks) {
                if (ks < 7) {                // prefetch next k-slice of x
                    #pragma unroll
                    for (int m = 0; m < 2; ++m) {
                        const float* ap = x + (size_t)(rw + m * 16 + cl) * KD
                                            + (ks + 1) * 32 + kg * 8;
                        f32x4 v0 = *(const f32x4*)ap;
                        f32x4 v1 = *(const f32x4*)(ap + 4);
                        #pragma unroll
                        for (int j = 0; j < 4; ++j) {
                            a_nxt[m][j]     = (short)f2bf(v0[j]);
                            a_nxt[m][4 + j] = (short)f2bf(v1[j]);
                        }
                    }
                }
                #pragma unroll
                for (int n = 0; n < 8; ++n) {
                    int lc = n * 16 + cl;                 // local col
                    int kc = ((ks << 2) | kg) ^ s;        // swizzled 16B chunk
                    short8 b = *(const short8*)((char*)Bs + (size_t)lc * 512 + (kc << 4));
                    // swapped operands: D[w-col][x-row]
                    acc[0][n] = __builtin_amdgcn_mfma_f32_16x16x32_bf16(b, a_cur[0], acc[0][n], 0, 0, 0);
                    acc[1][n] = __builtin_amdgcn_mfma_f32_16x16x32_bf16(b, a_cur[1], acc[1][n], 0, 0, 0);
                }
                a_cur[0] = a_nxt[0];
                a_cur[1] = a_nxt[1];
            }

            // ---- epilogue: rows rw+m*16+cl, cols c0+n*16+kg*4 (plain stores) ----
            #pragma unroll
            for (int m = 0; m < 2; ++m) {
                int tym = (m == 0) ? ty0 : ty1;
                if (tym == t) {
                    float* orow = out + (size_t)(rw + m * 16 + cl) * ND + c0 + kg * 4;
                    #pragma unroll
                    for (int n = 0; n < 8; ++n) {
                        f32x4 bv = *(const f32x4*)(bias + (size_t)t * ND + c0 + n * 16 + kg * 4);
                        *(f32x4*)(orow + n * 16) = acc[m][n] + bv;
                    }
                }
            }
        }
    }
}

extern "C" void kernel_launch(void* const* d_in, const int* in_sizes, int n_in,
                              void* d_out, int out_size, void* d_ws, size_t ws_size,
                              hipStream_t stream) {
    const float* x    = (const float*)d_in[0];
    const int*   tv   = (const int*)d_in[1];
    const float* w    = (const float*)d_in[2];
    const float* bias = (const float*)d_in[3];
    float* out = (float*)d_out;
    unsigned short* wT = (unsigned short*)d_ws;   // 8*256*256*2 = 1 MiB

    prep_weights<<<dim3(256), dim3(256), 0, stream>>>(w, wT);
    hetero_gemm<<<dim3(NBLK), dim3(512), 0, stream>>>(x, tv, wT, bias, out);
}

// Round 10
// 76.319 us; speedup vs baseline: 1.5388x; 1.5388x over previous
//
#include <hip/hip_runtime.h>
#include <hip/hip_bf16.h>

// HeteroLinear fused forward on gfx950: out[i] = x[i] @ W[tv[i]] + b[tv[i]]
// N=131072, IN=OUT=256, T=8, tv sorted. HBM floor ~256 MB -> ~41 us.
// R10 = R9 with ONE change: __launch_bounds__(512) (no min-waves arg).
// R9's (512,4) resolved to a 64-VGPR clamp (measured) -> worst spill yet
// (WRITE 208 MB). R8 measured real pressure 104 VGPR for this same compute
// body; 104 <= 128 means 2 blocks/CU co-schedule naturally with 64 KB LDS.
// Occupancy is controlled by LDS size ONLY; launch-bounds min-waves is
// untrustworthy for 8-wave blocks (R2/R9 evidence).

#define NROWS 131072
#define KD 256
#define ND 256
#define BM 256                      // rows per block
#define NBLK (NROWS / BM)           // 512
#define HC 128                      // cols per staged half

typedef __attribute__((ext_vector_type(8))) short short8;
typedef __attribute__((ext_vector_type(4))) float f32x4;
typedef __attribute__((ext_vector_type(4))) float flt4;

typedef __attribute__((address_space(3))) unsigned int lds_u32_t;
typedef __attribute__((address_space(1))) unsigned int glb_u32_t;

__device__ inline unsigned short f2bf(float f) {
    unsigned int u = __float_as_uint(f);
    u += 0x7FFFu + ((u >> 16) & 1u);   // RNE
    return (unsigned short)(u >> 16);
}

// ---- weight prep: wT[t][n][k] = bf16(w[t][k][n]) ----
__global__ __launch_bounds__(256) void prep_weights(const float* __restrict__ w,
                                                    unsigned short* __restrict__ wT) {
    __shared__ unsigned short L[8][264];
    const int t  = blockIdx.x >> 5;
    const int k0 = (blockIdx.x & 31) * 8;
    const int tid = threadIdx.x;

    #pragma unroll
    for (int i = 0; i < 2; ++i) {
        int idx = i * 256 + tid;
        int kr  = idx >> 6;
        int nq  = idx & 63;
        const flt4* src = (const flt4*)(w + ((size_t)t * 256 + k0 + kr) * 256);
        flt4 v = src[nq];
        #pragma unroll
        for (int j = 0; j < 4; ++j) L[kr][nq * 4 + j] = f2bf(v[j]);
    }
    __syncthreads();

    int n = tid;
    short8 v;
    #pragma unroll
    for (int j = 0; j < 8; ++j) v[j] = (short)L[j][n];
    *(short8*)(wT + ((size_t)t * 256 + n) * 256 + k0) = v;
}

// ---- main GEMM ----
__global__ __launch_bounds__(512) void hetero_gemm(
        const float* __restrict__ x, const int* __restrict__ tv,
        const unsigned short* __restrict__ wT, const float* __restrict__ bias,
        float* __restrict__ out) {
    // Half of W[t]: 128 cols x 256 k, bf16, [local col][k], 512 B per col,
    // XOR-swizzled 16B chunks: LDS chunk c of col holds global chunk c^(col&7).
    __shared__ short Bs[HC * KD];            // 64 KiB -> 2 blocks/CU

    const int tid  = threadIdx.x;
    const int lane = tid & 63;
    const int wv   = tid >> 6;               // 8 waves
    const int cl   = lane & 15;
    const int kg   = lane >> 4;
    const int r0   = blockIdx.x * BM;
    const int rw   = r0 + wv * 32;           // wave's 32-row strip

    const int tmin = tv[r0];
    const int tmax = tv[r0 + BM - 1];
    const int ty0  = tv[rw + cl];            // type of row (m=0)
    const int ty1  = tv[rw + 16 + cl];       // type of row (m=1)
    const int s    = cl & 7;                 // swizzle key (col&7 == cl&7)

    for (int t = tmin; t <= tmax; ++t) {
        #pragma unroll
        for (int half = 0; half < 2; ++half) {
            const int c0 = half * HC;

            if (t > tmin || half > 0)
                __syncthreads();             // all reads of prev half done

            // ---- stage W[t][c0..c0+127][*] -> LDS: 4096 chunks, 8 rounds ----
            {
                const unsigned short* Wt = wT + (size_t)t * (KD * ND);
                #pragma unroll
                for (int rnd = 0; rnd < 8; ++rnd) {
                    int i   = rnd * 512 + tid;   // chunk 0..4095
                    int lc  = i >> 5;            // local col 0..127
                    int c   = i & 31;
                    int sc  = c ^ (lc & 7);      // source-side swizzle
                    const unsigned short* gp = Wt + (size_t)(c0 + lc) * KD + sc * 8;
                    __builtin_amdgcn_global_load_lds(
                        (const glb_u32_t*)gp,
                        (lds_u32_t*)((char*)Bs + (size_t)(rnd * 512 + wv * 64) * 16),
                        16, 0, 0);
                }
            }
            __syncthreads();                 // drain DMA; half ready

            // ---- compute 32 rows x this col-half ----
            f32x4 zero = {0.f, 0.f, 0.f, 0.f};
            f32x4 acc[2][8];
            #pragma unroll
            for (int m = 0; m < 2; ++m)
                #pragma unroll
                for (int n = 0; n < 8; ++n) acc[m][n] = zero;

            short8 a_cur[2], a_nxt[2];
            #pragma unroll
            for (int m = 0; m < 2; ++m) {    // preload ks=0
                const float* ap = x + (size_t)(rw + m * 16 + cl) * KD + kg * 8;
                f32x4 v0 = *(const f32x4*)ap;
                f32x4 v1 = *(const f32x4*)(ap + 4);
                #pragma unroll
                for (int j = 0; j < 4; ++j) {
                    a_cur[m][j]     = (short)f2bf(v0[j]);
                    a_cur[m][4 + j] = (short)f2bf(v1[j]);
                }
            }

            #pragma unroll
            for (int ks = 0; ks < 8; ++ks) {
                if (ks < 7) {                // prefetch next k-slice of x
                    #pragma unroll
                    for (int m = 0; m < 2; ++m) {
                        const float* ap = x + (size_t)(rw + m * 16 + cl) * KD
                                            + (ks + 1) * 32 + kg * 8;
                        f32x4 v0 = *(const f32x4*)ap;
                        f32x4 v1 = *(const f32x4*)(ap + 4);
                        #pragma unroll
                        for (int j = 0; j < 4; ++j) {
                            a_nxt[m][j]     = (short)f2bf(v0[j]);
                            a_nxt[m][4 + j] = (short)f2bf(v1[j]);
                        }
                    }
                }
                #pragma unroll
                for (int n = 0; n < 8; ++n) {
                    int lc = n * 16 + cl;                 // local col
                    int kc = ((ks << 2) | kg) ^ s;        // swizzled 16B chunk
                    short8 b = *(const short8*)((char*)Bs + (size_t)lc * 512 + (kc << 4));
                    // swapped operands: D[w-col][x-row]
                    acc[0][n] = __builtin_amdgcn_mfma_f32_16x16x32_bf16(b, a_cur[0], acc[0][n], 0, 0, 0);
                    acc[1][n] = __builtin_amdgcn_mfma_f32_16x16x32_bf16(b, a_cur[1], acc[1][n], 0, 0, 0);
                }
                a_cur[0] = a_nxt[0];
                a_cur[1] = a_nxt[1];
            }

            // ---- epilogue: rows rw+m*16+cl, cols c0+n*16+kg*4 (plain stores) ----
            #pragma unroll
            for (int m = 0; m < 2; ++m) {
                int tym = (m == 0) ? ty0 : ty1;
                if (tym == t) {
                    float* orow = out + (size_t)(rw + m * 16 + cl) * ND + c0 + kg * 4;
                    #pragma unroll
                    for (int n = 0; n < 8; ++n) {
                        f32x4 bv = *(const f32x4*)(bias + (size_t)t * ND + c0 + n * 16 + kg * 4);
                        *(f32x4*)(orow + n * 16) = acc[m][n] + bv;
                    }
                }
            }
        }
    }
}

extern "C" void kernel_launch(void* const* d_in, const int* in_sizes, int n_in,
                              void* d_out, int out_size, void* d_ws, size_t ws_size,
                              hipStream_t stream) {
    const float* x    = (const float*)d_in[0];
    const int*   tv   = (const int*)d_in[1];
    const float* w    = (const float*)d_in[2];
    const float* bias = (const float*)d_in[3];
    float* out = (float*)d_out;
    unsigned short* wT = (unsigned short*)d_ws;   // 8*256*256*2 = 1 MiB

    prep_weights<<<dim3(256), dim3(256), 0, stream>>>(w, wT);
    hetero_gemm<<<dim3(NBLK), dim3(512), 0, stream>>>(x, tv, wT, bias, out);
}